// Round 12
// baseline (186.927 us; speedup 1.0000x reference)
//
#include <hip/hip_runtime.h>

#define C2 0.17677669529663687f  // 1/(4*sqrt(2))

typedef __attribute__((ext_vector_type(8))) short short8;
typedef __attribute__((ext_vector_type(8))) unsigned short ushort8;
typedef __attribute__((ext_vector_type(4))) float f32x4;

__device__ __forceinline__ unsigned short f2bf(float x) {
    union { float f; unsigned u; } v; v.f = x;
    unsigned r = v.u + 0x7fffu + ((v.u >> 16) & 1u);
    return (unsigned short)(r >> 16);
}
__device__ __forceinline__ float bf2f(unsigned short u) {
    union { unsigned u; float f; } v; v.u = ((unsigned)u) << 16;
    return v.f;
}

// ---------------- in-block split-K MFMA GEMM, 32x64 tile (R11) ----------------
__device__ __forceinline__ void gemm_inblk_splitk(
    const float* __restrict__ A, const float* __restrict__ W,
    float* __restrict__ out, int row0, int n0, int outcol0, int ldw, int outld)
{
    __shared__ unsigned short Al[2][2][32][40];
    __shared__ unsigned short Bl[2][2][64][40];
    __shared__ float red[32][65];
    const int tid = threadIdx.x;
    const int g = tid >> 8;
    const int t = tid & 255;
    const int lane = t & 63, w4 = t >> 6;
    const int quad = lane >> 4, lr = lane & 15;
    const int k0base = g * 384;

    f32x4 acc[2] = {{0.f,0.f,0.f,0.f},{0.f,0.f,0.f,0.f}};

    float4 ra, rb[2];
    {
        ra = *(const float4*)&A[(size_t)(row0 + (t >> 3)) * 768 + k0base + (t & 7) * 4];
        #pragma unroll
        for (int l = 0; l < 2; ++l) {
            int idy = t + l * 256;
            rb[l] = *(const float4*)&W[(size_t)(k0base + (idy >> 4)) * ldw + n0 + (idy & 15) * 4];
        }
    }
    {
        *(ushort4*)&Al[g][0][t >> 3][(t & 7) * 4] =
            make_ushort4(f2bf(ra.x), f2bf(ra.y), f2bf(ra.z), f2bf(ra.w));
        #pragma unroll
        for (int l = 0; l < 2; ++l) {
            int idy = t + l * 256;
            int kr = idy >> 4, nq = (idy & 15) * 4;
            int col = (((kr >> 3) ^ ((idy & 15) >> 2)) << 3) | (kr & 7);
            Bl[g][0][nq + 0][col] = f2bf(rb[l].x);
            Bl[g][0][nq + 1][col] = f2bf(rb[l].y);
            Bl[g][0][nq + 2][col] = f2bf(rb[l].z);
            Bl[g][0][nq + 3][col] = f2bf(rb[l].w);
        }
    }
    __syncthreads();

    const int ITER = 12;
    #pragma unroll
    for (int i = 0; i < ITER; ++i) {
        const int cur = i & 1, nxt = cur ^ 1;
        float4 na, nb[2];
        if (i + 1 < ITER) {
            int kn = k0base + (i + 1) * 32;
            na = *(const float4*)&A[(size_t)(row0 + (t >> 3)) * 768 + kn + (t & 7) * 4];
            #pragma unroll
            for (int l = 0; l < 2; ++l) {
                int idy = t + l * 256;
                nb[l] = *(const float4*)&W[(size_t)(kn + (idy >> 4)) * ldw + n0 + (idy & 15) * 4];
            }
        }
        short8 af[2], bfr;
        af[0] = *(const short8*)&Al[g][cur][lr][quad << 3];
        af[1] = *(const short8*)&Al[g][cur][16 + lr][quad << 3];
        {
            int csw = quad ^ (w4 & 3);
            bfr = *(const short8*)&Bl[g][cur][w4 * 16 + lr][csw << 3];
        }
        acc[0] = __builtin_amdgcn_mfma_f32_16x16x32_bf16(af[0], bfr, acc[0], 0, 0, 0);
        acc[1] = __builtin_amdgcn_mfma_f32_16x16x32_bf16(af[1], bfr, acc[1], 0, 0, 0);
        if (i + 1 < ITER) {
            *(ushort4*)&Al[g][nxt][t >> 3][(t & 7) * 4] =
                make_ushort4(f2bf(na.x), f2bf(na.y), f2bf(na.z), f2bf(na.w));
            #pragma unroll
            for (int l = 0; l < 2; ++l) {
                int idy = t + l * 256;
                int kr = idy >> 4, nq = (idy & 15) * 4;
                int col = (((kr >> 3) ^ ((idy & 15) >> 2)) << 3) | (kr & 7);
                Bl[g][nxt][nq + 0][col] = f2bf(nb[l].x);
                Bl[g][nxt][nq + 1][col] = f2bf(nb[l].y);
                Bl[g][nxt][nq + 2][col] = f2bf(nb[l].z);
                Bl[g][nxt][nq + 3][col] = f2bf(nb[l].w);
            }
        }
        __syncthreads();
    }
    if (g == 1) {
        #pragma unroll
        for (int mi = 0; mi < 2; ++mi)
            #pragma unroll
            for (int r = 0; r < 4; ++r)
                red[mi * 16 + quad * 4 + r][w4 * 16 + lr] = acc[mi][r];
    }
    __syncthreads();
    if (g == 0) {
        #pragma unroll
        for (int mi = 0; mi < 2; ++mi)
            #pragma unroll
            for (int r = 0; r < 4; ++r) {
                int rr = mi * 16 + quad * 4 + r;
                out[(size_t)(row0 + rr) * outld + outcol0 + w4 * 16 + lr] =
                    acc[mi][r] + red[rr][w4 * 16 + lr];
            }
    }
}

// qkv GEMM + zero the per-head scan counters (consumed by chunk_state next dispatch)
__global__ __launch_bounds__(512) void gemm_qkv_mfma(
    const float* __restrict__ H, const float* __restrict__ Wq,
    const float* __restrict__ Wk, const float* __restrict__ Wv,
    float* __restrict__ out, int* __restrict__ counters)
{
    if (blockIdx.x == 0 && blockIdx.y == 0 && threadIdx.x < 12) counters[threadIdx.x] = 0;
    const int nt = blockIdx.x, mt = blockIdx.y;
    const float* W; int ldw, n0;
    if (nt < 3)      { W = Wq; ldw = 192; n0 = nt * 64; }
    else if (nt < 6) { W = Wk; ldw = 192; n0 = (nt - 3) * 64; }
    else             { W = Wv; ldw = 768; n0 = (nt - 6) * 64; }
    gemm_inblk_splitk(H, W, out, mt * 32, n0, nt * 64, ldw, 1152);
}

__global__ __launch_bounds__(512) void gemm_wo_mfma(
    const float* __restrict__ Y, const float* __restrict__ Wo, float* __restrict__ out)
{
    const int nt = blockIdx.x, mt = blockIdx.y;
    gemm_inblk_splitk(Y, Wo, out, mt * 32, nt * 64, nt * 64, 768, 768);
}

// ---------------- chunk state (512 thr, 8-wave split) + FUSED per-head exclusive scan ----------------
// Last-arriver of the 16 chunk blocks per head performs the scan (spin-free; fences + device atomics).
__global__ __launch_bounds__(512) void chunk_state_k(
    const float* __restrict__ qkv, unsigned short* __restrict__ St, float* __restrict__ z,
    int* __restrict__ counters)
{
    const int c = blockIdx.x, h = blockIdx.y;
    __shared__ float Kc[64][17];
    __shared__ unsigned short Pk[320][72];
    __shared__ unsigned short Vt[80][72];
    __shared__ int is_last;
    const int tid = threadIdx.x;
    const int lane = tid & 63, wave = tid >> 6;
    const int quad = lane >> 4, lr = lane & 15;

    if (tid < 256) {
        int s = tid >> 2, f4 = (tid & 3) * 4;
        float4 kv = *(const float4*)&qkv[(size_t)(c * 64 + s) * 1152 + 192 + h * 16 + f4];
        Kc[s][f4 + 0] = kv.x; Kc[s][f4 + 1] = kv.y; Kc[s][f4 + 2] = kv.z; Kc[s][f4 + 3] = kv.w;
    }
    #pragma unroll
    for (int l = 0; l < 2; ++l) {
        int idx = tid + l * 512;
        int s = idx >> 4, d4 = (idx & 15) * 4;
        float4 vv = *(const float4*)&qkv[(size_t)(c * 64 + s) * 1152 + 384 + h * 64 + d4];
        Vt[d4 + 0][s] = f2bf(vv.x);
        Vt[d4 + 1][s] = f2bf(vv.y);
        Vt[d4 + 2][s] = f2bf(vv.z);
        Vt[d4 + 3][s] = f2bf(vv.w);
    }
    for (int idx = tid; idx < 1152; idx += 512) {
        int rr = 64 + idx / 72, ss = idx % 72;
        Vt[rr][ss] = (rr == 64 && ss < 64) ? (unsigned short)0x3F80 : (unsigned short)0;
    }
    __syncthreads();
    for (int idx = tid; idx < 2880; idx += 512) {
        int n = idx / 9, s8 = (idx % 9) * 8;
        short8 v8;
        #pragma unroll
        for (int tt = 0; tt < 8; ++tt) {
            int s = s8 + tt;
            float ph = 0.f;
            if (s < 64 && n < 273) {
                if (n == 0) ph = 1.f;
                else if (n < 17) ph = Kc[s][n - 1] * 0.5f;
                else { int m = n - 17; ph = Kc[s][m >> 4] * Kc[s][m & 15] * C2; }
            }
            v8[tt] = (short)f2bf(ph);
        }
        *(short8*)&Pk[n][s8] = v8;
    }
    __syncthreads();

    const int mg = wave & 1, ng = wave >> 1;   // ng 0..3
    const int MT = mg ? 2 : 3, mbase = mg ? 3 : 0;
    f32x4 acc[3][5];
    #pragma unroll
    for (int a = 0; a < 3; ++a)
        #pragma unroll
        for (int b = 0; b < 5; ++b) acc[a][b] = (f32x4){0.f, 0.f, 0.f, 0.f};
    #pragma unroll
    for (int ks = 0; ks < 2; ++ks) {
        short8 af[3], bfr[5];
        for (int mt = 0; mt < MT; ++mt)
            af[mt] = *(const short8*)&Vt[(mbase + mt) * 16 + lr][ks * 32 + quad * 8];
        #pragma unroll
        for (int nt = 0; nt < 5; ++nt)
            bfr[nt] = *(const short8*)&Pk[(ng * 5 + nt) * 16 + lr][ks * 32 + quad * 8];
        for (int mt = 0; mt < MT; ++mt)
            #pragma unroll
            for (int nt = 0; nt < 5; ++nt)
                acc[mt][nt] = __builtin_amdgcn_mfma_f32_16x16x32_bf16(af[mt], bfr[nt], acc[mt][nt], 0, 0, 0);
    }
    unsigned short* Sbt = St + (size_t)(h * 16 + c) * 18432;
    float* zb = z + (size_t)(h * 16 + c) * 273;
    #pragma unroll
    for (int nt = 0; nt < 5; ++nt) {
        int n = (ng * 5 + nt) * 16 + lr;
        if (n < 273) {
            for (int mt = 0; mt < MT; ++mt) {
                int mtile = mbase + mt;
                if (mtile < 4) {
                    #pragma unroll
                    for (int r = 0; r < 4; ++r)
                        Sbt[(mtile * 16 + quad * 4 + r) * 288 + n] = f2bf(acc[mt][nt][r]);
                } else if (quad == 0) {
                    zb[n] = acc[mt][nt][0];   // d==64 ones-row -> z
                }
            }
        }
    }

    // ---- fused per-head exclusive scan (last arriver of the 16 chunk blocks) ----
    __syncthreads();                       // drains vmem (compiler emits vmcnt(0) before barrier)
    if (tid == 0) {
        __threadfence();                   // release
        int prev = atomicAdd(&counters[h], 1);
        is_last = (prev == 15) ? 1 : 0;
    }
    __syncthreads();
    if (is_last) {
        __threadfence();                   // acquire
        unsigned short* Sh = St + (size_t)h * 16 * 18432;
        for (int idx = tid; idx < 64 * 35; idx += 512) {
            int d = idx / 35, gq = idx % 35;
            if (gq < 34) {
                unsigned short* p = Sh + d * 288 + gq * 8;
                float run[8] = {0.f,0.f,0.f,0.f,0.f,0.f,0.f,0.f};
                for (int cc = 0; cc < 16; ++cc) {
                    ushort8 v = *(ushort8*)&p[(size_t)cc * 18432];
                    ushort8 o;
                    #pragma unroll
                    for (int tt = 0; tt < 8; ++tt) { o[tt] = f2bf(run[tt]); run[tt] += bf2f(v[tt]); }
                    *(ushort8*)&p[(size_t)cc * 18432] = o;
                }
            } else {
                unsigned short* p = Sh + d * 288 + 272;
                float run = 0.f;
                for (int cc = 0; cc < 16; ++cc) {
                    float v = bf2f(p[(size_t)cc * 18432]);
                    p[(size_t)cc * 18432] = f2bf(run);
                    run += v;
                }
            }
        }
        float* zh = z + (size_t)h * 16 * 273;
        for (int idx = tid; idx < 273; idx += 512) {
            float* p = zh + idx;
            float run = 0.f;
            for (int cc = 0; cc < 16; ++cc) { float v = p[cc * 273]; p[cc * 273] = run; run += v; }
        }
    }
}

// ---------------- chunk output (512 thr, 8 waves x 2 MFMA-tiles), reads pre-scanned states ----------------
__global__ __launch_bounds__(512) void chunk_out_k(
    const float* __restrict__ qkv, const unsigned short* __restrict__ St, const float* __restrict__ z,
    float* __restrict__ y)
{
    const int c = blockIdx.x, h = blockIdx.y;
    __shared__ float Qc[64][17];
    __shared__ unsigned short Aq[64][40];
    __shared__ unsigned short Kb[64][40];
    __shared__ unsigned short Pq[64][360];
    __shared__ unsigned short Sv[64][360];
    __shared__ float zl[288];
    __shared__ float dpart[12][64];        // 0..7 phiQ.z per wave, 8..11 score rowsums per n-tile
    const int tid = threadIdx.x;
    const int lane = tid & 63, wave = tid >> 6;       // wave 0..7
    const int quad = lane >> 4, lr = lane & 15;
    const int wm = wave & 1;                          // QK^T m-half
    const int wn4 = wave >> 1;                        // QK^T n-tile 0..3

    if (tid < 256) {
        int s = tid >> 2, f4 = (tid & 3) * 4;
        const float* base = &qkv[(size_t)(c * 64 + s) * 1152 + h * 16];
        float4 qv = *(const float4*)&base[f4];
        float4 kv = *(const float4*)&base[192 + f4];
        Qc[s][f4 + 0] = qv.x; Qc[s][f4 + 1] = qv.y; Qc[s][f4 + 2] = qv.z; Qc[s][f4 + 3] = qv.w;
        *(ushort4*)&Aq[s][f4] = make_ushort4(f2bf(qv.x), f2bf(qv.y), f2bf(qv.z), f2bf(qv.w));
        *(ushort4*)&Kb[s][f4] = make_ushort4(f2bf(kv.x), f2bf(kv.y), f2bf(kv.z), f2bf(kv.w));
        *(ushort4*)&Aq[s][16 + (tid & 3) * 4] = make_ushort4(0, 0, 0, 0);
        *(ushort4*)&Kb[s][16 + (tid & 3) * 4] = make_ushort4(0, 0, 0, 0);
    }
    #pragma unroll
    for (int l = 0; l < 2; ++l) {                    // V -> Sv cols 288..351
        int idx = tid + l * 512;
        int s = idx >> 4, d4 = (idx & 15) * 4;
        float4 vv = *(const float4*)&qkv[(size_t)(c * 64 + s) * 1152 + 384 + h * 64 + d4];
        Sv[d4 + 0][288 + s] = f2bf(vv.x);
        Sv[d4 + 1][288 + s] = f2bf(vv.y);
        Sv[d4 + 2][288 + s] = f2bf(vv.z);
        Sv[d4 + 3][288 + s] = f2bf(vv.w);
    }
    const unsigned short* Sgt = St + (size_t)(h * 16 + c) * 18432;
    for (int idx = tid; idx < 2176; idx += 512) {    // S^T rows -> Sv cols 0..271
        int d = idx / 34, n8 = (idx % 34) * 8;
        *(ushort8*)&Sv[d][n8] = *(const ushort8*)&Sgt[d * 288 + n8];
    }
    if (tid < 64) Sv[tid][272] = Sgt[tid * 288 + 272];
    for (int idx = tid; idx < 960; idx += 512) {     // zero cols 273..287
        int d = idx / 15, n = 273 + idx % 15;
        Sv[d][n] = 0;
    }
    const float* zg = z + (size_t)(h * 16 + c) * 273;
    for (int idx = tid; idx < 288; idx += 512) zl[idx] = (idx < 273) ? zg[idx] : 0.f;
    __syncthreads();

    // QK^T: 16 tiles over 8 waves (2 each)
    f32x4 accS[2] = {{0.f,0.f,0.f,0.f},{0.f,0.f,0.f,0.f}};
    {
        short8 afq[2], bfk;
        #pragma unroll
        for (int mi = 0; mi < 2; ++mi)
            afq[mi] = *(const short8*)&Aq[wm * 32 + mi * 16 + lr][quad * 8];
        bfk = *(const short8*)&Kb[wn4 * 16 + lr][quad * 8];
        #pragma unroll
        for (int mi = 0; mi < 2; ++mi)
            accS[mi] = __builtin_amdgcn_mfma_f32_16x16x32_bf16(afq[mi], bfk, accS[mi], 0, 0, 0);
    }

    // phiQ build + z-dot (wave covers n in [36w, 36w+36); 8*36 = 288 exactly)
    {
        int i = lane;
        float qr[16];
        #pragma unroll
        for (int f = 0; f < 16; ++f) qr[f] = Qc[i][f];
        float dp = 0.f;
        int n0 = wave * 36;
        for (int n = n0; n < n0 + 36; ++n) {
            float ph;
            if (n == 0) ph = 1.f;
            else if (n < 17) ph = qr[n - 1] * 0.5f;
            else if (n < 273) { int m = n - 17; ph = qr[m >> 4] * qr[m & 15] * C2; }
            else ph = 0.f;
            Pq[i][n] = f2bf(ph);
            dp += ph * zl[n];
        }
        dpart[wave][i] = dp;
    }

    // scores: poly + mask on C-frags; rowsum within this wave's 16-col tile; write bf16 to Pq 288+
    #pragma unroll
    for (int mi = 0; mi < 2; ++mi) {
        float rs[4];
        #pragma unroll
        for (int r = 0; r < 4; ++r) {
            int i = wm * 32 + mi * 16 + quad * 4 + r;
            int j = wn4 * 16 + lr;
            float u = accS[mi][r];
            float sc = (j <= i) ? (1.f + 0.25f * u + u * u * (1.f / 32.f)) : 0.f;
            rs[r] = sc;
            Pq[i][288 + j] = f2bf(sc);
        }
        #pragma unroll
        for (int r = 0; r < 4; ++r) {
            float v = rs[r];
            v += __shfl_xor(v, 1);
            v += __shfl_xor(v, 2);
            v += __shfl_xor(v, 4);
            v += __shfl_xor(v, 8);
            if (lr == 0) dpart[8 + wn4][wm * 32 + mi * 16 + quad * 4 + r] = v;
        }
    }
    __syncthreads();

    // main fused MFMA: wave w -> m-tile (w>>1), n-tiles (w&1)*2 + {0,1}; K = 352 (11 ksteps)
    const int mt = wave >> 1, nh = wave & 1;
    f32x4 acc[2] = {{0.f,0.f,0.f,0.f},{0.f,0.f,0.f,0.f}};
    #pragma unroll
    for (int ks = 0; ks < 11; ++ks) {
        short8 af = *(const short8*)&Pq[mt * 16 + lr][ks * 32 + quad * 8];
        short8 b0 = *(const short8*)&Sv[nh * 32 + lr][ks * 32 + quad * 8];
        short8 b1 = *(const short8*)&Sv[nh * 32 + 16 + lr][ks * 32 + quad * 8];
        acc[0] = __builtin_amdgcn_mfma_f32_16x16x32_bf16(af, b0, acc[0], 0, 0, 0);
        acc[1] = __builtin_amdgcn_mfma_f32_16x16x32_bf16(af, b1, acc[1], 0, 0, 0);
    }

    #pragma unroll
    for (int r = 0; r < 4; ++r) {
        int i = mt * 16 + quad * 4 + r;
        float den = 1e-12f;
        #pragma unroll
        for (int p = 0; p < 12; ++p) den += dpart[p][i];
        float rden = 1.f / den;
        #pragma unroll
        for (int ni = 0; ni < 2; ++ni)
            y[(size_t)(c * 64 + i) * 768 + h * 64 + nh * 32 + ni * 16 + lr] = acc[ni][r] * rden;
    }
}

extern "C" void kernel_launch(void* const* d_in, const int* in_sizes, int n_in,
                              void* d_out, int out_size, void* d_ws, size_t ws_size,
                              hipStream_t stream) {
    const float* hs = (const float*)d_in[0];
    const float* Wq = (const float*)d_in[1];
    const float* Wk = (const float*)d_in[2];
    const float* Wv = (const float*)d_in[3];
    const float* Wo = (const float*)d_in[4];
    float* out = (float*)d_out;
    float* ws  = (float*)d_ws;

    float* qkv = ws;                                        // 1024*1152 fp32
    float* yb  = ws + 1179648;                              // 1024*768 fp32
    unsigned short* St = (unsigned short*)(ws + 1966080);   // 192 x 64 x 288 bf16
    float* zb  = ws + 5320704;                              // 192 x 273 fp32
    int* counters = (int*)(ws + 5373120);                   // 12 ints (zeroed by gemm_qkv)

    gemm_qkv_mfma<<<dim3(18, 32), 512, 0, stream>>>(hs, Wq, Wk, Wv, qkv, counters);
    chunk_state_k<<<dim3(16, 12), 512, 0, stream>>>(qkv, St, zb, counters);
    chunk_out_k  <<<dim3(16, 12), 512, 0, stream>>>(qkv, St, zb, yb);
    gemm_wo_mfma <<<dim3(12, 32), 512, 0, stream>>>(yb, Wo, out);
}

// Round 13
// 161.642 us; speedup vs baseline: 1.1564x; 1.1564x over previous
//
#include <hip/hip_runtime.h>

#define C2 0.17677669529663687f  // 1/(4*sqrt(2))

typedef __attribute__((ext_vector_type(8))) short short8;
typedef __attribute__((ext_vector_type(8))) unsigned short ushort8;
typedef __attribute__((ext_vector_type(4))) float f32x4;

__device__ __forceinline__ unsigned short f2bf(float x) {
    union { float f; unsigned u; } v; v.f = x;
    unsigned r = v.u + 0x7fffu + ((v.u >> 16) & 1u);
    return (unsigned short)(r >> 16);
}
__device__ __forceinline__ float bf2f(unsigned short u) {
    union { unsigned u; float f; } v; v.u = ((unsigned)u) << 16;
    return v.f;
}

// ---------------- in-block split-K MFMA GEMM, 32x64 tile (R11-verified) ----------------
__device__ __forceinline__ void gemm_inblk_splitk(
    const float* __restrict__ A, const float* __restrict__ W,
    float* __restrict__ out, int row0, int n0, int outcol0, int ldw, int outld)
{
    __shared__ unsigned short Al[2][2][32][40];
    __shared__ unsigned short Bl[2][2][64][40];
    __shared__ float red[32][65];
    const int tid = threadIdx.x;
    const int g = tid >> 8;
    const int t = tid & 255;
    const int lane = t & 63, w4 = t >> 6;
    const int quad = lane >> 4, lr = lane & 15;
    const int k0base = g * 384;

    f32x4 acc[2] = {{0.f,0.f,0.f,0.f},{0.f,0.f,0.f,0.f}};

    float4 ra, rb[2];
    {
        ra = *(const float4*)&A[(size_t)(row0 + (t >> 3)) * 768 + k0base + (t & 7) * 4];
        #pragma unroll
        for (int l = 0; l < 2; ++l) {
            int idy = t + l * 256;
            rb[l] = *(const float4*)&W[(size_t)(k0base + (idy >> 4)) * ldw + n0 + (idy & 15) * 4];
        }
    }
    {
        *(ushort4*)&Al[g][0][t >> 3][(t & 7) * 4] =
            make_ushort4(f2bf(ra.x), f2bf(ra.y), f2bf(ra.z), f2bf(ra.w));
        #pragma unroll
        for (int l = 0; l < 2; ++l) {
            int idy = t + l * 256;
            int kr = idy >> 4, nq = (idy & 15) * 4;
            int col = (((kr >> 3) ^ ((idy & 15) >> 2)) << 3) | (kr & 7);
            Bl[g][0][nq + 0][col] = f2bf(rb[l].x);
            Bl[g][0][nq + 1][col] = f2bf(rb[l].y);
            Bl[g][0][nq + 2][col] = f2bf(rb[l].z);
            Bl[g][0][nq + 3][col] = f2bf(rb[l].w);
        }
    }
    __syncthreads();

    const int ITER = 12;
    #pragma unroll
    for (int i = 0; i < ITER; ++i) {
        const int cur = i & 1, nxt = cur ^ 1;
        float4 na, nb[2];
        if (i + 1 < ITER) {
            int kn = k0base + (i + 1) * 32;
            na = *(const float4*)&A[(size_t)(row0 + (t >> 3)) * 768 + kn + (t & 7) * 4];
            #pragma unroll
            for (int l = 0; l < 2; ++l) {
                int idy = t + l * 256;
                nb[l] = *(const float4*)&W[(size_t)(kn + (idy >> 4)) * ldw + n0 + (idy & 15) * 4];
            }
        }
        short8 af[2], bfr;
        af[0] = *(const short8*)&Al[g][cur][lr][quad << 3];
        af[1] = *(const short8*)&Al[g][cur][16 + lr][quad << 3];
        {
            int csw = quad ^ (w4 & 3);
            bfr = *(const short8*)&Bl[g][cur][w4 * 16 + lr][csw << 3];
        }
        acc[0] = __builtin_amdgcn_mfma_f32_16x16x32_bf16(af[0], bfr, acc[0], 0, 0, 0);
        acc[1] = __builtin_amdgcn_mfma_f32_16x16x32_bf16(af[1], bfr, acc[1], 0, 0, 0);
        if (i + 1 < ITER) {
            *(ushort4*)&Al[g][nxt][t >> 3][(t & 7) * 4] =
                make_ushort4(f2bf(na.x), f2bf(na.y), f2bf(na.z), f2bf(na.w));
            #pragma unroll
            for (int l = 0; l < 2; ++l) {
                int idy = t + l * 256;
                int kr = idy >> 4, nq = (idy & 15) * 4;
                int col = (((kr >> 3) ^ ((idy & 15) >> 2)) << 3) | (kr & 7);
                Bl[g][nxt][nq + 0][col] = f2bf(nb[l].x);
                Bl[g][nxt][nq + 1][col] = f2bf(nb[l].y);
                Bl[g][nxt][nq + 2][col] = f2bf(nb[l].z);
                Bl[g][nxt][nq + 3][col] = f2bf(nb[l].w);
            }
        }
        __syncthreads();
    }
    if (g == 1) {
        #pragma unroll
        for (int mi = 0; mi < 2; ++mi)
            #pragma unroll
            for (int r = 0; r < 4; ++r)
                red[mi * 16 + quad * 4 + r][w4 * 16 + lr] = acc[mi][r];
    }
    __syncthreads();
    if (g == 0) {
        #pragma unroll
        for (int mi = 0; mi < 2; ++mi)
            #pragma unroll
            for (int r = 0; r < 4; ++r) {
                int rr = mi * 16 + quad * 4 + r;
                out[(size_t)(row0 + rr) * outld + outcol0 + w4 * 16 + lr] =
                    acc[mi][r] + red[rr][w4 * 16 + lr];
            }
    }
}

// qkv: hidden(1024x768) @ [Wq|Wk|Wv] -> qkv(1024x1152). grid (18,32) x 512
__global__ __launch_bounds__(512) void gemm_qkv_mfma(
    const float* __restrict__ H, const float* __restrict__ Wq,
    const float* __restrict__ Wk, const float* __restrict__ Wv,
    float* __restrict__ out)
{
    const int nt = blockIdx.x, mt = blockIdx.y;
    const float* W; int ldw, n0;
    if (nt < 3)      { W = Wq; ldw = 192; n0 = nt * 64; }
    else if (nt < 6) { W = Wk; ldw = 192; n0 = (nt - 3) * 64; }
    else             { W = Wv; ldw = 768; n0 = (nt - 6) * 64; }
    gemm_inblk_splitk(H, W, out, mt * 32, n0, nt * 64, ldw, 1152);
}

// wo: y(1024x768) @ Wo(768x768) -> out(1024x768). grid (12,32) x 512
__global__ __launch_bounds__(512) void gemm_wo_mfma(
    const float* __restrict__ Y, const float* __restrict__ Wo, float* __restrict__ out)
{
    const int nt = blockIdx.x, mt = blockIdx.y;
    gemm_inblk_splitk(Y, Wo, out, mt * 32, nt * 64, nt * 64, 768, 768);
}

// ---------------- chunk state (512 thr, 8-wave split; NO fused scan) ----------------
__global__ __launch_bounds__(512) void chunk_state_k(
    const float* __restrict__ qkv, unsigned short* __restrict__ St, float* __restrict__ z)
{
    const int c = blockIdx.x, h = blockIdx.y;
    __shared__ float Kc[64][17];
    __shared__ unsigned short Pk[320][72];
    __shared__ unsigned short Vt[80][72];
    const int tid = threadIdx.x;
    const int lane = tid & 63, wave = tid >> 6;
    const int quad = lane >> 4, lr = lane & 15;

    if (tid < 256) {
        int s = tid >> 2, f4 = (tid & 3) * 4;
        float4 kv = *(const float4*)&qkv[(size_t)(c * 64 + s) * 1152 + 192 + h * 16 + f4];
        Kc[s][f4 + 0] = kv.x; Kc[s][f4 + 1] = kv.y; Kc[s][f4 + 2] = kv.z; Kc[s][f4 + 3] = kv.w;
    }
    #pragma unroll
    for (int l = 0; l < 2; ++l) {
        int idx = tid + l * 512;
        int s = idx >> 4, d4 = (idx & 15) * 4;
        float4 vv = *(const float4*)&qkv[(size_t)(c * 64 + s) * 1152 + 384 + h * 64 + d4];
        Vt[d4 + 0][s] = f2bf(vv.x);
        Vt[d4 + 1][s] = f2bf(vv.y);
        Vt[d4 + 2][s] = f2bf(vv.z);
        Vt[d4 + 3][s] = f2bf(vv.w);
    }
    for (int idx = tid; idx < 1152; idx += 512) {
        int rr = 64 + idx / 72, ss = idx % 72;
        Vt[rr][ss] = (rr == 64 && ss < 64) ? (unsigned short)0x3F80 : (unsigned short)0;
    }
    __syncthreads();
    for (int idx = tid; idx < 2880; idx += 512) {
        int n = idx / 9, s8 = (idx % 9) * 8;
        short8 v8;
        #pragma unroll
        for (int tt = 0; tt < 8; ++tt) {
            int s = s8 + tt;
            float ph = 0.f;
            if (s < 64 && n < 273) {
                if (n == 0) ph = 1.f;
                else if (n < 17) ph = Kc[s][n - 1] * 0.5f;
                else { int m = n - 17; ph = Kc[s][m >> 4] * Kc[s][m & 15] * C2; }
            }
            v8[tt] = (short)f2bf(ph);
        }
        *(short8*)&Pk[n][s8] = v8;
    }
    __syncthreads();

    const int mg = wave & 1, ng = wave >> 1;   // ng 0..3
    const int MT = mg ? 2 : 3, mbase = mg ? 3 : 0;
    f32x4 acc[3][5];
    #pragma unroll
    for (int a = 0; a < 3; ++a)
        #pragma unroll
        for (int b = 0; b < 5; ++b) acc[a][b] = (f32x4){0.f, 0.f, 0.f, 0.f};
    #pragma unroll
    for (int ks = 0; ks < 2; ++ks) {
        short8 af[3], bfr[5];
        for (int mt = 0; mt < MT; ++mt)
            af[mt] = *(const short8*)&Vt[(mbase + mt) * 16 + lr][ks * 32 + quad * 8];
        #pragma unroll
        for (int nt = 0; nt < 5; ++nt)
            bfr[nt] = *(const short8*)&Pk[(ng * 5 + nt) * 16 + lr][ks * 32 + quad * 8];
        for (int mt = 0; mt < MT; ++mt)
            #pragma unroll
            for (int nt = 0; nt < 5; ++nt)
                acc[mt][nt] = __builtin_amdgcn_mfma_f32_16x16x32_bf16(af[mt], bfr[nt], acc[mt][nt], 0, 0, 0);
    }
    unsigned short* Sbt = St + (size_t)(h * 16 + c) * 18432;
    float* zb = z + (size_t)(h * 16 + c) * 273;
    #pragma unroll
    for (int nt = 0; nt < 5; ++nt) {
        int n = (ng * 5 + nt) * 16 + lr;
        if (n < 273) {
            for (int mt = 0; mt < MT; ++mt) {
                int mtile = mbase + mt;
                if (mtile < 4) {
                    #pragma unroll
                    for (int r = 0; r < 4; ++r)
                        Sbt[(mtile * 16 + quad * 4 + r) * 288 + n] = f2bf(acc[mt][nt][r]);
                } else if (quad == 0) {
                    zb[n] = acc[mt][nt][0];   // d==64 ones-row -> z
                }
            }
        }
    }
}

// ---------------- exclusive prefix over 16 chunks (dedicated flat dispatch — R11-verified) ----------------
__global__ __launch_bounds__(256) void scan_state_k(unsigned short* __restrict__ St, float* __restrict__ z)
{
    const int NS = 12 * 64 * 273;   // 209,664
    int e = blockIdx.x * 256 + threadIdx.x;
    if (e < NS) {
        int hh = e / (64 * 273), rem = e % (64 * 273);
        int d = rem / 273, n = rem % 273;
        unsigned short* p = St + (size_t)hh * 16 * 18432 + d * 288 + n;
        float run = 0.f;
        #pragma unroll
        for (int c = 0; c < 16; ++c) {
            float v = bf2f(p[c * 18432]);
            p[c * 18432] = f2bf(run);
            run += v;
        }
    } else if (e < NS + 12 * 273) {
        int e2 = e - NS, hh = e2 / 273, n = e2 % 273;
        float* p = z + hh * 16 * 273 + n;
        float run = 0.f;
        #pragma unroll
        for (int c = 0; c < 16; ++c) { float v = p[c * 273]; p[c * 273] = run; run += v; }
    }
}

// ---------------- chunk output (512 thr, 8 waves x 2 MFMA-tiles; R12-verified body) ----------------
__global__ __launch_bounds__(512) void chunk_out_k(
    const float* __restrict__ qkv, const unsigned short* __restrict__ St, const float* __restrict__ z,
    float* __restrict__ y)
{
    const int c = blockIdx.x, h = blockIdx.y;
    __shared__ float Qc[64][17];
    __shared__ unsigned short Aq[64][40];
    __shared__ unsigned short Kb[64][40];
    __shared__ unsigned short Pq[64][360];
    __shared__ unsigned short Sv[64][360];
    __shared__ float zl[288];
    __shared__ float dpart[12][64];
    const int tid = threadIdx.x;
    const int lane = tid & 63, wave = tid >> 6;       // 0..7
    const int quad = lane >> 4, lr = lane & 15;
    const int wm = wave & 1;
    const int wn4 = wave >> 1;

    if (tid < 256) {
        int s = tid >> 2, f4 = (tid & 3) * 4;
        const float* base = &qkv[(size_t)(c * 64 + s) * 1152 + h * 16];
        float4 qv = *(const float4*)&base[f4];
        float4 kv = *(const float4*)&base[192 + f4];
        Qc[s][f4 + 0] = qv.x; Qc[s][f4 + 1] = qv.y; Qc[s][f4 + 2] = qv.z; Qc[s][f4 + 3] = qv.w;
        *(ushort4*)&Aq[s][f4] = make_ushort4(f2bf(qv.x), f2bf(qv.y), f2bf(qv.z), f2bf(qv.w));
        *(ushort4*)&Kb[s][f4] = make_ushort4(f2bf(kv.x), f2bf(kv.y), f2bf(kv.z), f2bf(kv.w));
        *(ushort4*)&Aq[s][16 + (tid & 3) * 4] = make_ushort4(0, 0, 0, 0);
        *(ushort4*)&Kb[s][16 + (tid & 3) * 4] = make_ushort4(0, 0, 0, 0);
    }
    #pragma unroll
    for (int l = 0; l < 2; ++l) {
        int idx = tid + l * 512;
        int s = idx >> 4, d4 = (idx & 15) * 4;
        float4 vv = *(const float4*)&qkv[(size_t)(c * 64 + s) * 1152 + 384 + h * 64 + d4];
        Sv[d4 + 0][288 + s] = f2bf(vv.x);
        Sv[d4 + 1][288 + s] = f2bf(vv.y);
        Sv[d4 + 2][288 + s] = f2bf(vv.z);
        Sv[d4 + 3][288 + s] = f2bf(vv.w);
    }
    const unsigned short* Sgt = St + (size_t)(h * 16 + c) * 18432;
    for (int idx = tid; idx < 2176; idx += 512) {
        int d = idx / 34, n8 = (idx % 34) * 8;
        *(ushort8*)&Sv[d][n8] = *(const ushort8*)&Sgt[d * 288 + n8];
    }
    if (tid < 64) Sv[tid][272] = Sgt[tid * 288 + 272];
    for (int idx = tid; idx < 960; idx += 512) {
        int d = idx / 15, n = 273 + idx % 15;
        Sv[d][n] = 0;
    }
    const float* zg = z + (size_t)(h * 16 + c) * 273;
    for (int idx = tid; idx < 288; idx += 512) zl[idx] = (idx < 273) ? zg[idx] : 0.f;
    __syncthreads();

    // QK^T: 16 tiles over 8 waves (2 each)
    f32x4 accS[2] = {{0.f,0.f,0.f,0.f},{0.f,0.f,0.f,0.f}};
    {
        short8 afq[2], bfk;
        #pragma unroll
        for (int mi = 0; mi < 2; ++mi)
            afq[mi] = *(const short8*)&Aq[wm * 32 + mi * 16 + lr][quad * 8];
        bfk = *(const short8*)&Kb[wn4 * 16 + lr][quad * 8];
        #pragma unroll
        for (int mi = 0; mi < 2; ++mi)
            accS[mi] = __builtin_amdgcn_mfma_f32_16x16x32_bf16(afq[mi], bfk, accS[mi], 0, 0, 0);
    }

    // phiQ build + z-dot (wave covers n in [36w, 36w+36))
    {
        int i = lane;
        float qr[16];
        #pragma unroll
        for (int f = 0; f < 16; ++f) qr[f] = Qc[i][f];
        float dp = 0.f;
        int n0 = wave * 36;
        for (int n = n0; n < n0 + 36; ++n) {
            float ph;
            if (n == 0) ph = 1.f;
            else if (n < 17) ph = qr[n - 1] * 0.5f;
            else if (n < 273) { int m = n - 17; ph = qr[m >> 4] * qr[m & 15] * C2; }
            else ph = 0.f;
            Pq[i][n] = f2bf(ph);
            dp += ph * zl[n];
        }
        dpart[wave][i] = dp;
    }

    // scores: poly + mask; rowsum within this wave's 16-col tile; write bf16 to Pq 288+
    #pragma unroll
    for (int mi = 0; mi < 2; ++mi) {
        float rs[4];
        #pragma unroll
        for (int r = 0; r < 4; ++r) {
            int i = wm * 32 + mi * 16 + quad * 4 + r;
            int j = wn4 * 16 + lr;
            float u = accS[mi][r];
            float sc = (j <= i) ? (1.f + 0.25f * u + u * u * (1.f / 32.f)) : 0.f;
            rs[r] = sc;
            Pq[i][288 + j] = f2bf(sc);
        }
        #pragma unroll
        for (int r = 0; r < 4; ++r) {
            float v = rs[r];
            v += __shfl_xor(v, 1);
            v += __shfl_xor(v, 2);
            v += __shfl_xor(v, 4);
            v += __shfl_xor(v, 8);
            if (lr == 0) dpart[8 + wn4][wm * 32 + mi * 16 + quad * 4 + r] = v;
        }
    }
    __syncthreads();

    // main fused MFMA: wave w -> m-tile (w>>1), n-half (w&1); K = 352 (11 ksteps)
    const int mt = wave >> 1, nh = wave & 1;
    f32x4 acc[2] = {{0.f,0.f,0.f,0.f},{0.f,0.f,0.f,0.f}};
    #pragma unroll
    for (int ks = 0; ks < 11; ++ks) {
        short8 af = *(const short8*)&Pq[mt * 16 + lr][ks * 32 + quad * 8];
        short8 b0 = *(const short8*)&Sv[nh * 32 + lr][ks * 32 + quad * 8];
        short8 b1 = *(const short8*)&Sv[nh * 32 + 16 + lr][ks * 32 + quad * 8];
        acc[0] = __builtin_amdgcn_mfma_f32_16x16x32_bf16(af, b0, acc[0], 0, 0, 0);
        acc[1] = __builtin_amdgcn_mfma_f32_16x16x32_bf16(af, b1, acc[1], 0, 0, 0);
    }

    #pragma unroll
    for (int r = 0; r < 4; ++r) {
        int i = mt * 16 + quad * 4 + r;
        float den = 1e-12f;
        #pragma unroll
        for (int p = 0; p < 12; ++p) den += dpart[p][i];
        float rden = 1.f / den;
        #pragma unroll
        for (int ni = 0; ni < 2; ++ni)
            y[(size_t)(c * 64 + i) * 768 + h * 64 + nh * 32 + ni * 16 + lr] = acc[ni][r] * rden;
    }
}

extern "C" void kernel_launch(void* const* d_in, const int* in_sizes, int n_in,
                              void* d_out, int out_size, void* d_ws, size_t ws_size,
                              hipStream_t stream) {
    const float* hs = (const float*)d_in[0];
    const float* Wq = (const float*)d_in[1];
    const float* Wk = (const float*)d_in[2];
    const float* Wv = (const float*)d_in[3];
    const float* Wo = (const float*)d_in[4];
    float* out = (float*)d_out;
    float* ws  = (float*)d_ws;

    float* qkv = ws;                                        // 1024*1152 fp32
    float* yb  = ws + 1179648;                              // 1024*768 fp32
    unsigned short* St = (unsigned short*)(ws + 1966080);   // 192 x 64 x 288 bf16
    float* zb  = ws + 5320704;                              // 192 x 273 fp32

    gemm_qkv_mfma<<<dim3(18, 32), 512, 0, stream>>>(hs, Wq, Wk, Wv, qkv);
    chunk_state_k<<<dim3(16, 12), 512, 0, stream>>>(qkv, St, zb);
    scan_state_k <<<832, 256, 0, stream>>>(St, zb);
    chunk_out_k  <<<dim3(16, 12), 512, 0, stream>>>(qkv, St, zb, yb);
    gemm_wo_mfma <<<dim3(12, 32), 512, 0, stream>>>(yb, Wo, out);
}